// Round 6
// baseline (16829.323 us; speedup 1.0000x reference)
//
#include <hip/hip_runtime.h>
#include <math.h>

// 2-layer LSTM decoder, H=100, T=8192 encode + F=1024 future steps, fp32.
// Three persistent blocks (3 CUs), 512 threads (8 waves) each:
//   block 0 (A) : layer-1 recurrence. gates1 = w_ih1*x + w_hh1*h1 + b. h1 -> ring1.
//   block 1 (A2): feed-forward pre2 = w_ih2*h1 + biases. ring1 -> ring2.
//                 8 INDEPENDENT waves, no barriers, 1-deep load pipeline.
//   block 2 (B) : layer-2 recurrence gates2 = pre2 + w_hh2*h2; y = h2.w_lin + b.
//
// V6: ONE ROW PER THREAD. V3/V4/V5 all failed to keep 200 weight floats/thread
// resident (VGPR stuck ~116-132: RA remats loads from L2, or spills pinned
// values to scratch = same L2 traffic; 160KB/CU/step ~ 3000cy = measured
// 1.7us/step). Fix demand, not the allocator: 512 threads, each owns ONE gate
// row (100 weights = 25 float4 ~ 100 VGPRs, total demand ~150 < 256 budget
// from __launch_bounds__(512,2) + waves_per_eu(2,2)) -> loads stay hoisted and
// resident. Weight base pointers laundered through opaque asm so invariant-
// load remat into the loop is also illegal. Certificate: VGPR ~150-200.
//
// Gate lane mapping (A,B): wave w owns cells 16w..16w+15 (w<7); lane l has
// (cell, gate) = (16w + (l&15), l>>4), row j = cell + 100*gate. Gather of
// i/f/g/o for the c-update is 3 intra-wave __shfl's -> still 1 barrier/step.
//
// Sync design (V3-proven, widened to 8 per-wave flags):
//  * Cross-CU data via relaxed agent atomics; ordering via s_waitcnt vmcnt only.
//    NO agent fences (whole-L2 wbl2/inv = V2 regression).
//  * Per-wave flags aw[8]/p2w[8]; consumers take min8. Producers publish at
//    top-of-next-iteration (store acks aged -> vmcnt cheap). Publish precedes
//    all blocking waits -> future-phase serial chain never deadlocks.
//  * A/B: raw s_barrier + lgkmcnt(0) only. A2: counted vmcnt(2) certify,
//    1-deep prefetch pipeline in encode, straight mode in future.
//  * Flags monotone <= 9217 -> 0xAA workspace poison sanitizes to 0.

#define HH 100
#define NT 512
#define ROWS 400
#define SPIN_CAP 2000000u

#define OFF_AW     0       // unsigned aw[8]  : A per-wave publish counters
#define OFF_P2W    128     // unsigned p2w[8] : A2 per-wave publish counters
#define OFF_BPROG  256     // unsigned        : B consumption counter
#define OFF_YPROG  384     // unsigned        : y produced counter
#define OFF_YSLOT  512     // float[F+1]
#define OFF_RING   16384

#define VMCNT0() asm volatile("s_waitcnt vmcnt(0)" ::: "memory")
#define VMCNT2() asm volatile("s_waitcnt vmcnt(2)" ::: "memory")
#define LGKM0()  asm volatile("s_waitcnt lgkmcnt(0)" ::: "memory")
#define CLOB()   asm volatile("" ::: "memory")

__device__ __forceinline__ float rl(float v, int k) {
    return __int_as_float(__builtin_amdgcn_readlane(__float_as_int(v), k));
}
__device__ __forceinline__ unsigned san(unsigned v) { return v > 0x00FFFFFFu ? 0u : v; }
__device__ __forceinline__ unsigned ldu(const unsigned* p) {
    return san(__hip_atomic_load((unsigned*)p, __ATOMIC_RELAXED, __HIP_MEMORY_SCOPE_AGENT));
}
__device__ __forceinline__ void stu(unsigned* p, unsigned v) {
    __hip_atomic_store(p, v, __ATOMIC_RELAXED, __HIP_MEMORY_SCOPE_AGENT);
}
__device__ __forceinline__ float ld_f(const float* p) {
    return __hip_atomic_load((float*)p, __ATOMIC_RELAXED, __HIP_MEMORY_SCOPE_AGENT);
}
__device__ __forceinline__ void st_wt(float* p, float v) {
    __hip_atomic_store(p, v, __ATOMIC_RELAXED, __HIP_MEMORY_SCOPE_AGENT);
}
__device__ __forceinline__ void wait_ge(unsigned* p, unsigned need, unsigned& cache) {
    if (cache >= need) return;
    unsigned s = 0;
    do { cache = ldu(p); } while (cache < need && ++s < SPIN_CAP);
    VMCNT0();
}
__device__ __forceinline__ void wait_min8(unsigned* q, unsigned need, unsigned& cache) {
    if (cache >= need) return;
    unsigned s = 0;
    for (;;) {
        unsigned m0 = ldu(q), m1 = ldu(q + 1), m2 = ldu(q + 2), m3 = ldu(q + 3);
        unsigned m4 = ldu(q + 4), m5 = ldu(q + 5), m6 = ldu(q + 6), m7 = ldu(q + 7);
        unsigned a = m0 < m1 ? m0 : m1, b = m2 < m3 ? m2 : m3;
        unsigned c = m4 < m5 ? m4 : m5, d = m6 < m7 ? m6 : m7;
        a = a < b ? a : b;  c = c < d ? c : d;
        cache = a < c ? a : c;
        if (cache >= need || ++s > SPIN_CAP) break;
    }
    VMCNT0();
}
// Raw workgroup barrier: LDS drain only (ring stores stay in flight).
__device__ __forceinline__ void bar() {
    LGKM0();
    __builtin_amdgcn_s_barrier();
    CLOB();
}
__device__ __forceinline__ float fast_sigm(float x) {
    return __builtin_amdgcn_rcpf(1.0f + __expf(-x));
}
__device__ __forceinline__ float fast_tanh(float x) {
    return fmaf(-2.0f, __builtin_amdgcn_rcpf(1.0f + __expf(2.0f * x)), 1.0f);
}
// Launder a pointer through opaque asm: the compiler can no longer prove the
// pointee invariant -> loads through it cannot be rematerialized in the loop.
__device__ __forceinline__ const float4* opqp(const float4* p) {
    unsigned long long u = (unsigned long long)p;
    asm("" : "+v"(u));
    return (const float4*)u;
}

// ---- weight registers: 25 float4 chunks, one row per thread ----
#define REP25(M) M(0) M(1) M(2) M(3) M(4) M(5) M(6) M(7) M(8) M(9) M(10) M(11) \
                 M(12) M(13) M(14) M(15) M(16) M(17) M(18) M(19) M(20) M(21) M(22) M(23) M(24)
#define DECLW(i) float4 W_##i;
#define LOADW(i) W_##i = wrow[i];
// chunk i covers h[4i..4i+3]; i<16 broadcast from hv0, i>=16 from hv1 (k<36)
#define DOTC(i) { \
    const float hsv = ((i) < 16) ? hv0 : hv1; \
    const int kb = ((i) < 16) ? (4 * (i)) : (4 * ((i) - 16)); \
    float h0 = rl(hsv, kb), h1 = rl(hsv, kb + 1), h2 = rl(hsv, kb + 2), h3 = rl(hsv, kb + 3); \
    a0 = fmaf(W_##i.x, h0, a0); a1 = fmaf(W_##i.y, h1, a1); \
    a0 = fmaf(W_##i.z, h2, a0); a1 = fmaf(W_##i.w, h3, a1); \
}

extern "C" __global__ void __launch_bounds__(NT, 2)
__attribute__((amdgpu_waves_per_eu(2, 2)))
decoder_kernel(const float* __restrict__ input,
               const float* __restrict__ enc_h,
               const float* __restrict__ enc_c,
               const float* __restrict__ w_ih1,
               const float* __restrict__ w_hh1,
               const float* __restrict__ b_ih1,
               const float* __restrict__ b_hh1,
               const float* __restrict__ w_ih2,
               const float* __restrict__ w_hh2,
               const float* __restrict__ b_ih2,
               const float* __restrict__ b_hh2,
               const float* __restrict__ w_lin,
               const float* __restrict__ b_lin,
               float* __restrict__ out,
               char* __restrict__ ws,
               int T, int F, int S)
{
    const int tid = threadIdx.x;
    const int l = tid & 63;
    const int w = tid >> 6;            // 8 waves
    unsigned* aw     = (unsigned*)(ws + OFF_AW);
    unsigned* p2w    = (unsigned*)(ws + OFF_P2W);
    unsigned* b_prog = (unsigned*)(ws + OFF_BPROG);
    unsigned* y_prog = (unsigned*)(ws + OFF_YPROG);
    float* y_slot = (float*)(ws + OFF_YSLOT);
    float* ring1  = (float*)(ws + OFF_RING);
    float* ring2  = ring1 + (size_t)S * HH;
    const int smask = S - 1;
    const int TOT = T + F;

    // Gate lane mapping for A and B (1 row per thread):
    const int cell = 16 * w + (l & 15);
    const int gate = l >> 4;                 // 0=i 1=f 2=g 3=o
    const bool valid = (cell < 100);
    const bool c_lane = (gate == 0) && valid;

    if (blockIdx.x == 0) {
        // ================= A: layer-1 recurrence =================
        __shared__ __align__(16) float h1s[2][128];
        const int j = valid ? (cell + 100 * gate) : 0;
        const float4* wrow = opqp((const float4*)(w_hh1 + (size_t)j * HH));
        REP25(DECLW)
        REP25(LOADW)
        const float wx = w_ih1[j];
        const float bi = b_ih1[j] + b_hh1[j];
        float cst = c_lane ? enc_c[cell] : 0.f;
        if (tid < 128) {
            h1s[0][tid] = (tid < HH) ? enc_h[tid] : 0.f;
            h1s[1][tid] = 0.f;
        }
        __syncthreads();

        unsigned cp2 = 0, cy = 0;
        for (int t = 0; t < TOT; ++t) {
            // publish slot t-1 (per wave): stores issued pre-barrier, vmcnt drains ack.
            VMCNT0();
            if (l == 0 && t > 0) stu(&aw[w], (unsigned)t);     // slots <= t-1 valid
            float x = 0.f;
            if (t < T) x = input[t];
            // ring1 overwrite guard: A2 consumed slot t-S when min(p2w) >= t-S+1
            if (t >= S) wait_min8(p2w, (unsigned)(t - S + 1), cp2);
            float hv0 = h1s[t & 1][l];
            float hv1 = h1s[t & 1][64 + l];    // slots 100-127 stay 0, never readlaned >=36
            float a0 = 0.f, a1 = 0.f;
            REP25(DOTC)
            float acc = bi + a0 + a1;
            if (t >= T) {                       // future: dot done, now wait for y
                wait_ge(y_prog, (unsigned)(t - T + 1), cy);
                x = ld_f(&y_slot[t - T]);
            }
            acc = fmaf(x, wx, acc);
            float v = (gate == 2) ? fast_tanh(acc) : fast_sigm(acc);
            float gf = __shfl(v, (l & 15) + 16);
            float gg = __shfl(v, (l & 15) + 32);
            float go = __shfl(v, (l & 15) + 48);
            if (c_lane) {
                cst = fmaf(gf, cst, v * gg);
                float h = go * fast_tanh(cst);
                h1s[(t + 1) & 1][cell] = h;
                st_wt(&ring1[(size_t)(t & smask) * HH + cell], h);
            }
            bar();    // LDS-only drain; ring1 stores stay in flight across it
        }
        VMCNT0();
        if (l == 0) stu(&aw[w], (unsigned)TOT);
    } else if (blockIdx.x == 1) {
        // ===== A2: pre2 = w_ih2*h1 + biases. 8 independent waves, no barriers. =====
        const bool av = (tid < ROWS);
        const int j = av ? tid : 0;
        const float4* wrow = opqp((const float4*)(w_ih2 + (size_t)j * HH));
        REP25(DECLW)
        REP25(LOADW)
        const float bi = b_ih2[j] + b_hh2[j];

        unsigned ca = 0, cb = 0;
        // ---- prologue: load slot 0
        wait_min8(aw, 1u, ca);
        float cv0 = ld_f(ring1 + l);
        float cv1 = (l < 36) ? ld_f(ring1 + 64 + l) : 0.f;
        // ---- pipelined encode: iter t stores slot t-1, prefetches slot t.
        // Per iter vm ops: 2 loads + 1 store. VMCNT2 at top -> all but the last
        // 2 ops acked -> store of slot t-3 certainly acked -> publish t-2.
        for (int t = 1; t < T; ++t) {
            VMCNT2();
            if (l == 0 && t >= 3) stu(&p2w[w], (unsigned)(t - 2));  // slots <= t-3 valid
            if (t - 1 >= S) wait_ge(b_prog, (unsigned)(t - S), cb); // overwrite guard
            wait_min8(aw, (unsigned)(t + 1), ca);                   // slot t readable
            const float* rp = ring1 + (size_t)(t & smask) * HH;
            float nv0 = ld_f(rp + l);
            float nv1 = (l < 36) ? ld_f(rp + 64 + l) : 0.f;
            float hv0 = cv0, hv1 = cv1;
            float a0 = 0.f, a1 = 0.f;
            REP25(DOTC)                                             // h(t-1)
            float* wpp = ring2 + (size_t)((t - 1) & smask) * ROWS;
            if (av) st_wt(wpp + j, bi + a0 + a1);
            cv0 = nv0; cv1 = nv1;
        }
        // ---- boundary: drain pipeline, then slot T-1 straight.
        VMCNT0();
        if (l == 0) stu(&p2w[w], (unsigned)(T - 1));                // slots <= T-2 valid
        {
            if (T - 1 >= S) wait_ge(b_prog, (unsigned)(T - S), cb);
            float hv0 = cv0, hv1 = cv1;
            float a0 = 0.f, a1 = 0.f;
            REP25(DOTC)                                             // h(T-1)
            float* wpp = ring2 + (size_t)((T - 1) & smask) * ROWS;
            if (av) st_wt(wpp + j, bi + a0 + a1);
        }
        VMCNT0();
        if (l == 0) stu(&p2w[w], (unsigned)T);                      // slots <= T-1 valid
        // ---- future: straight mode (serial chain needs same-step data).
        for (int t = T; t < TOT; ++t) {
            if (t >= S) wait_ge(b_prog, (unsigned)(t - S + 1), cb);
            wait_min8(aw, (unsigned)(t + 1), ca);
            const float* rp = ring1 + (size_t)(t & smask) * HH;
            float hv0 = ld_f(rp + l);
            float hv1 = (l < 36) ? ld_f(rp + 64 + l) : 0.f;
            float a0 = 0.f, a1 = 0.f;
            REP25(DOTC)
            float* wpp = ring2 + (size_t)(t & smask) * ROWS;
            if (av) st_wt(wpp + j, bi + a0 + a1);
            VMCNT0();
            if (l == 0) stu(&p2w[w], (unsigned)(t + 1));
        }
    } else {
        // ================= B: layer-2 recurrence + output =================
        __shared__ __align__(16) float h2s[2][128];
        __shared__ float yw[2][8];
        const int j = valid ? (cell + 100 * gate) : 0;
        const float4* wrow = opqp((const float4*)(w_hh2 + (size_t)j * HH));
        REP25(DECLW)
        REP25(LOADW)
        const float wl = c_lane ? w_lin[cell] : 0.f;
        const float bl = b_lin[0];
        float cst = 0.f;
        if (tid < 128) { h2s[0][tid] = 0.f; h2s[1][tid] = 0.f; }
        __syncthreads();

        unsigned cpB = 0;
        for (int u = 0; u < TOT; ++u) {
            // Emit previous step's y right after its barrier.
            if (tid == 0 && u > 0) {
                const float* yq = yw[(u - 1) & 1];
                float y = yq[0] + yq[1] + yq[2] + yq[3] + yq[4] + yq[5] + yq[6] + bl;
                stu(b_prog, (unsigned)u);        // ring2 slot u-1 consumed pre-barrier
                if (u - 1 >= T - 1) {
                    st_wt(&y_slot[(u - 1) - (T - 1)], y);
                    VMCNT0();                    // y_slot store acked before flag
                    stu(y_prog, (unsigned)(u - T + 1));
                }
                out[u - 1] = y;
            }
            float hv0 = h2s[u & 1][l];
            float hv1 = h2s[u & 1][64 + l];
            const float* pp = ring2 + (size_t)(u & smask) * ROWS;
            float pre;
            float a0 = 0.f, a1 = 0.f;
            if (u < T) {     // encode: wait first so pre2 load latency hides under dot
                wait_min8(p2w, (unsigned)(u + 1), cpB);
                pre = ld_f(pp + j);
                REP25(DOTC)
            } else {         // future: local dot first, then wait
                REP25(DOTC)
                wait_min8(p2w, (unsigned)(u + 1), cpB);
                pre = ld_f(pp + j);
            }
            float acc = pre + a0 + a1;
            float v = (gate == 2) ? fast_tanh(acc) : fast_sigm(acc);
            float gf = __shfl(v, (l & 15) + 16);
            float gg = __shfl(v, (l & 15) + 32);
            float go = __shfl(v, (l & 15) + 48);
            float py = 0.f;
            if (c_lane) {
                cst = fmaf(gf, cst, v * gg);
                float h = go * fast_tanh(cst);
                h2s[(u + 1) & 1][cell] = h;
                py = h * wl;
            }
            // reduce cells 16w..16w+15 (lanes 0-15; lanes >=16 carry 0)
            py += __shfl_down(py, 8);
            py += __shfl_down(py, 4);
            py += __shfl_down(py, 2);
            py += __shfl_down(py, 1);
            if (l == 0 && w < 7) yw[u & 1][w] = py;
            bar();
        }
        if (tid == 0) {   // final step's y
            const float* yq = yw[(TOT - 1) & 1];
            out[TOT - 1] = yq[0] + yq[1] + yq[2] + yq[3] + yq[4] + yq[5] + yq[6] + bl;
        }
    }
}

extern "C" void kernel_launch(void* const* d_in, const int* in_sizes, int n_in,
                              void* d_out, int out_size, void* d_ws, size_t ws_size,
                              hipStream_t stream) {
    const float* input = (const float*)d_in[0];
    const float* enc_h = (const float*)d_in[1];
    const float* enc_c = (const float*)d_in[2];
    const float* w_ih1 = (const float*)d_in[3];
    const float* w_hh1 = (const float*)d_in[4];
    const float* b_ih1 = (const float*)d_in[5];
    const float* b_hh1 = (const float*)d_in[6];
    const float* w_ih2 = (const float*)d_in[7];
    const float* w_hh2 = (const float*)d_in[8];
    const float* b_ih2 = (const float*)d_in[9];
    const float* b_hh2 = (const float*)d_in[10];
    const float* w_lin = (const float*)d_in[11];
    const float* b_lin = (const float*)d_in[12];
    (void)n_in;

    int T = in_sizes[0];
    int F = out_size - T;
    if (F < 0) F = 0;

    // largest power-of-two ring slot count that fits both rings in d_ws
    int S = 16;
    while ((size_t)OFF_RING + (size_t)S * 2 * (HH + ROWS) * 4 <= ws_size && S < 8192)
        S <<= 1;

    decoder_kernel<<<dim3(3), dim3(NT), 0, stream>>>(
        input, enc_h, enc_c, w_ih1, w_hh1, b_ih1, b_hh1,
        w_ih2, w_hh2, b_ih2, b_hh2, w_lin, b_lin,
        (float*)d_out, (char*)d_ws, T, F, S);
}